// Round 8
// baseline (1191.111 us; speedup 1.0000x reference)
//
#include <hip/hip_runtime.h>

#define TT 2000
#define BB 64
#define HH 256
#define BH (BB*HH)
#define CH 16           // chunk = 16 time steps
#define NCH (TT/CH)     // 125 chunks

__device__ __forceinline__ float clip01(float x) { return fminf(fmaxf(x, 0.0f), 1.0f); }

// ---------------- weight prep ----------------
// w_inT[k][h] = w_in[h][k]                      (for GEMM)
// w_recP[s][4l+j] = w_rec[l+64j][s]             (per-lane float4 gather rows)
__global__ void transpose2(const float* __restrict__ w_in, const float* __restrict__ w_rec,
                           float* __restrict__ w_inT, float* __restrict__ w_recP) {
    int idx = blockIdx.x * 256 + threadIdx.x;   // 65536 per matrix
    int h = idx >> 8, s = idx & 255;            // coalesced read over s
    w_inT[s * HH + h] = w_in[idx];
    int l = h & 63, j = h >> 6;
    w_recP[s * HH + 4 * l + j] = w_rec[idx];
}

// ---------------- f32 GEMM: xw[n,h] = sum_k X[n,k] * w_inT[k,h] ----------------
#define BM 128
#define BN 128
#define BK 32
__global__ __launch_bounds__(256) void gemm_xw(const float* __restrict__ X,
                                               const float* __restrict__ WT,
                                               float* __restrict__ OutXW) {
    __shared__ __align__(16) float XsT[BK][BM + 4];   // transposed: [k][row]
    __shared__ __align__(16) float Ws[BK][BN + 4];    // [k][col]
    int tid = threadIdx.x;
    int n0 = blockIdx.x * BM;
    int h0 = blockIdx.y * BN;
    int ty = tid >> 4, tx = tid & 15;
    float acc[8][8] = {};

    for (int kc = 0; kc < HH; kc += BK) {
        {
            int r = tid & 127, kseg = (tid >> 7) * 16;
            const float* src = X + (size_t)(n0 + r) * HH + kc + kseg;
#pragma unroll
            for (int q = 0; q < 4; q++) {
                float4 xv = *(const float4*)(src + q * 4);
                XsT[kseg + q * 4 + 0][r] = xv.x;
                XsT[kseg + q * 4 + 1][r] = xv.y;
                XsT[kseg + q * 4 + 2][r] = xv.z;
                XsT[kseg + q * 4 + 3][r] = xv.w;
            }
        }
        {
            int krow = tid >> 3, cs = (tid & 7) * 16;
            const float* src = WT + (size_t)(kc + krow) * HH + h0 + cs;
#pragma unroll
            for (int q = 0; q < 4; q++) {
                float4 wv = *(const float4*)(src + q * 4);
                *(float4*)&Ws[krow][cs + q * 4] = wv;
            }
        }
        __syncthreads();
#pragma unroll 4
        for (int kk = 0; kk < BK; kk++) {
            float4 a0 = *(const float4*)&XsT[kk][ty * 8];
            float4 a1 = *(const float4*)&XsT[kk][ty * 8 + 4];
            float4 b0 = *(const float4*)&Ws[kk][tx * 8];
            float4 b1 = *(const float4*)&Ws[kk][tx * 8 + 4];
            float a[8] = {a0.x, a0.y, a0.z, a0.w, a1.x, a1.y, a1.z, a1.w};
            float bb[8] = {b0.x, b0.y, b0.z, b0.w, b1.x, b1.y, b1.z, b1.w};
#pragma unroll
            for (int r = 0; r < 8; r++)
#pragma unroll
                for (int c = 0; c < 8; c++)
                    acc[r][c] += a[r] * bb[c];
        }
        __syncthreads();
    }
#pragma unroll
    for (int r = 0; r < 8; r++) {
        int n = n0 + ty * 8 + r;
        int b = n / TT;
        int t = n - b * TT;
        float* dst = OutXW + ((size_t)t * BB + b) * HH + h0 + tx * 8;
        float4 s0 = {acc[r][0], acc[r][1], acc[r][2], acc[r][3]};
        float4 s1 = {acc[r][4], acc[r][5], acc[r][6], acc[r][7]};
        *(float4*)dst = s0;
        *(float4*)(dst + 4) = s1;
    }
}

// ---------------- sequential LIF scan ----------------
// Ownership h = lane + 64j (R6-verbatim dynamics/stores/sum order).
// Per mask j: up to 2 branchless gather slots (dummy row 63+64j with weight 0
// when empty -> fma(0,x,r)=r exact, fma(1,x,r)=x+r exact).
// Step order: dynamics -> ballot/stores -> ACCUMULATE prev slots (only vmcnt
// wait; loads are one full step old) -> ii update -> extract+issue current.
// >2 spikes in any mask (~3% of steps): blocking recompute of the whole sum in
// the same ascending order (identical fp), flagged for next step.

// extract up to 2 slots from mask M (bit index + 64*J = neuron), issue loads
#define GM(J, M, SL0, SL1, W0, W1) do {                                             \
    unsigned long long t0 = (M);                                                    \
    W0 = (t0 != 0ull) ? 1.0f : 0.0f;                                                \
    int s0 = (int)__builtin_ctzll(t0 | 0x8000000000000000ull);                      \
    unsigned long long t1 = t0 & (t0 - 1ull);                                       \
    W1 = (t1 != 0ull) ? 1.0f : 0.0f;                                                \
    int s1 = (int)__builtin_ctzll(t1 | 0x8000000000000000ull);                      \
    ov |= (t1 & (t1 - 1ull));                                                       \
    SL0 = *(const float4*)(w_recP + (((size_t)(s0 + 64 * J)) << 8) + 4 * lane);     \
    SL1 = *(const float4*)(w_recP + (((size_t)(s1 + 64 * J)) << 8) + 4 * lane);     \
} while (0)

// blocking full gather for mask M (ascending), into rex0..3
#define GBLK(J, M) { unsigned long long m = (M);                                    \
    while (m) { int s = (int)__builtin_ctzll(m) + 64 * J; m &= m - 1ull;            \
        float4 e = *(const float4*)(w_recP + ((size_t)s << 8) + 4 * lane);          \
        rex0 += e.x; rex1 += e.y; rex2 += e.z; rex3 += e.w; } }

#define STEP(CUR, PREROW) do {                                                      \
    bool z[4]; float id[4];                                                         \
    _Pragma("unroll")                                                               \
    for (int j = 0; j < 4; j++) {                                                   \
        float vd = vv[j] + am[j] * (ii[j] - vv[j]);     /* v + DT*tmi*(-v+i) */     \
        id[j] = ii[j] - bs[j] * ii[j];                  /* i - DT*tsi*i    */       \
        z[j] = (vd - 1.0f) > 0.0f;                                                  \
        float zf = z[j] ? 1.0f : 0.0f;                                              \
        vv[j] = z[j] ? 0.0f : vd;                                                   \
        __builtin_nontemporal_store(zf, &outp[stoff + j * 64]);                     \
        zl[j] = zf;                                                                 \
    }                                                                               \
    stoff += BH;                                                                    \
    unsigned long long m0 = __ballot(z[0]);                                         \
    unsigned long long m1 = __ballot(z[1]);                                         \
    unsigned long long m2 = __ballot(z[2]);                                         \
    unsigned long long m3 = __ballot(z[3]);                                         \
    float r0, r1, r2, r3;                                                           \
    if (fb) {                                                                       \
        r0 = rex0; r1 = rex1; r2 = rex2; r3 = rex3;                                 \
    } else {                                                                        \
        r0 = 0.f; r1 = 0.f; r2 = 0.f; r3 = 0.f;                                     \
        r0 += wt0 * sl0.x; r1 += wt0 * sl0.y; r2 += wt0 * sl0.z; r3 += wt0 * sl0.w; \
        r0 += wt1 * sl1.x; r1 += wt1 * sl1.y; r2 += wt1 * sl1.z; r3 += wt1 * sl1.w; \
        r0 += wt2 * sl2.x; r1 += wt2 * sl2.y; r2 += wt2 * sl2.z; r3 += wt2 * sl2.w; \
        r0 += wt3 * sl3.x; r1 += wt3 * sl3.y; r2 += wt3 * sl3.z; r3 += wt3 * sl3.w; \
        r0 += wt4 * sl4.x; r1 += wt4 * sl4.y; r2 += wt4 * sl4.z; r3 += wt4 * sl4.w; \
        r0 += wt5 * sl5.x; r1 += wt5 * sl5.y; r2 += wt5 * sl5.z; r3 += wt5 * sl5.w; \
        r0 += wt6 * sl6.x; r1 += wt6 * sl6.y; r2 += wt6 * sl6.z; r3 += wt6 * sl6.w; \
        r0 += wt7 * sl7.x; r1 += wt7 * sl7.y; r2 += wt7 * sl7.z; r3 += wt7 * sl7.w; \
    }                                                                               \
    ii[0] = (id[0] + CUR[0]) + r0; ii[1] = (id[1] + CUR[1]) + r1;                   \
    ii[2] = (id[2] + CUR[2]) + r2; ii[3] = (id[3] + CUR[3]) + r3;                   \
    PREROW;                                                                         \
    unsigned long long ov = 0ull;                                                   \
    GM(0, m0, sl0, sl1, wt0, wt1);                                                  \
    GM(1, m1, sl2, sl3, wt2, wt3);                                                  \
    GM(2, m2, sl4, sl5, wt4, wt5);                                                  \
    GM(3, m3, sl6, sl7, wt6, wt7);                                                  \
    fb = false;                                                                     \
    if (ov) {                                                                       \
        fb = true;                                                                  \
        rex0 = 0.f; rex1 = 0.f; rex2 = 0.f; rex3 = 0.f;                             \
        GBLK(0, m0); GBLK(1, m1); GBLK(2, m2); GBLK(3, m3);                         \
    }                                                                               \
} while (0)

__global__ __launch_bounds__(128) void scan_lif(const float* __restrict__ tau_syn,
                                                const float* __restrict__ tau_mem,
                                                const float* __restrict__ w_recP,
                                                float* __restrict__ outp) {
    const float DT = 0.001f;
    __shared__ __align__(16) float ring[2 * CH * HH];   // 32 KB: 2 slots x 16 rows x 1KB
    int b = blockIdx.x;
    int lane = threadIdx.x & 63;
    int wid = threadIdx.x >> 6;

    if (wid == 1) {
        // ---- producer: pre-stage chunk 0 into slot 0 ----
        float4 rb[CH];
#pragma unroll
        for (int r = 0; r < CH; ++r)
            rb[r] = *(const float4*)(outp + ((size_t)r * BB + b) * HH + 4 * lane);
#pragma unroll
        for (int r = 0; r < CH; ++r)
            *(float4*)&ring[r * HH + 4 * lane] = rb[r];
        __syncthreads();
        for (int c = 0; c < NCH; ++c) {
            if (c + 1 < NCH) {
                int t0 = (c + 1) * CH;
                int lb = ((c + 1) & 1) * (CH * HH);
                float4 sb[CH];
#pragma unroll
                for (int r = 0; r < CH; ++r)
                    sb[r] = *(const float4*)(outp + ((size_t)(t0 + r) * BB + b) * HH + 4 * lane);
#pragma unroll
                for (int r = 0; r < CH; ++r)
                    *(float4*)&ring[lb + r * HH + 4 * lane] = sb[r];
            }
            __syncthreads();
        }
        return;
    }

    // ---- consumer wave ----
    int off = b * HH + lane;
    float am[4], bs[4];
#pragma unroll
    for (int j = 0; j < 4; j++) {
        am[j] = DT * clip01(tau_mem[lane + 64 * j]);
        bs[j] = DT * clip01(tau_syn[lane + 64 * j]);
    }

    float vv[4] = {0.f, 0.f, 0.f, 0.f};
    float ii[4] = {0.f, 0.f, 0.f, 0.f};
    float zl[4] = {0.f, 0.f, 0.f, 0.f};
    float cur[4], nxt[4];
    float4 sl0 = {0,0,0,0}, sl1 = {0,0,0,0}, sl2 = {0,0,0,0}, sl3 = {0,0,0,0};
    float4 sl4 = {0,0,0,0}, sl5 = {0,0,0,0}, sl6 = {0,0,0,0}, sl7 = {0,0,0,0};
    float wt0 = 0.f, wt1 = 0.f, wt2 = 0.f, wt3 = 0.f;
    float wt4 = 0.f, wt5 = 0.f, wt6 = 0.f, wt7 = 0.f;
    float rex0 = 0.f, rex1 = 0.f, rex2 = 0.f, rex3 = 0.f;
    bool fb = false;
    unsigned stoff = (unsigned)off;

    __syncthreads();   // chunk 0 staged

    for (int c = 0; c < NCH; ++c) {
        int lb = (c & 1) * (CH * HH);
#pragma unroll
        for (int j = 0; j < 4; j++)
            cur[j] = ring[lb + lane + 64 * j];
        for (int u = 0; u < CH - 1; ++u) {
#pragma unroll
            for (int j = 0; j < 4; j++)
                nxt[j] = ring[lb + (u + 1) * HH + lane + 64 * j];
            STEP(cur, { cur[0] = nxt[0]; cur[1] = nxt[1]; cur[2] = nxt[2]; cur[3] = nxt[3]; });
            (void)0;
        }
        STEP(cur, ((void)0));   // u = CH-1
        __syncthreads();
    }

    // final state: z_f, v_f, i_f (all from registers)
#pragma unroll
    for (int j = 0; j < 4; j++) {
        outp[(size_t)TT * BH + b * HH + lane + 64 * j] = zl[j];
        outp[(size_t)TT * BH + BH + b * HH + lane + 64 * j] = vv[j];
        outp[(size_t)TT * BH + 2 * BH + b * HH + lane + 64 * j] = ii[j];
    }
}

extern "C" void kernel_launch(void* const* d_in, const int* in_sizes, int n_in,
                              void* d_out, int out_size, void* d_ws, size_t ws_size,
                              hipStream_t stream) {
    const float* x       = (const float*)d_in[0];
    const float* w_in    = (const float*)d_in[1];
    const float* w_rec   = (const float*)d_in[2];
    const float* tau_syn = (const float*)d_in[3];
    const float* tau_mem = (const float*)d_in[4];
    float* out = (float*)d_out;

    float* w_inT  = (float*)d_ws;           // 65536 floats
    float* w_recP = w_inT + HH * HH;        // 65536 floats

    transpose2<<<256, 256, 0, stream>>>(w_in, w_rec, w_inT, w_recP);

    dim3 ggrid((BB * TT) / BM, HH / BN);    // (1000, 2)
    gemm_xw<<<ggrid, 256, 0, stream>>>(x, w_inT, out);

    scan_lif<<<BB, 128, 0, stream>>>(tau_syn, tau_mem, w_recP, out);
}

// Round 9
// 499.864 us; speedup vs baseline: 2.3829x; 2.3829x over previous
//
#include <hip/hip_runtime.h>

#define TT 2000
#define BB 64
#define HH 256
#define BH (BB*HH)
#define CH 8            // chunk = 8 time steps (ring 16KB, leaves room for 128KB w-cache)
#define NCH (TT/CH)     // 250 chunks
#define CROWS 128       // w_recT rows cached in LDS (s in [0,128) = masks m0,m1)

__device__ __forceinline__ float clip01(float x) { return fminf(fmaxf(x, 0.0f), 1.0f); }

// ---------------- transpose both weight matrices (256KB each) ----------------
__global__ void transpose2(const float* __restrict__ w_in, const float* __restrict__ w_rec,
                           float* __restrict__ w_inT, float* __restrict__ w_recT) {
    int idx = blockIdx.x * 256 + threadIdx.x;   // 65536 per matrix
    int k = idx >> 8, h = idx & 255;
    w_inT[idx]  = w_in[h * HH + k];             // w_inT[k][h] = w_in[h][k]
    w_recT[idx] = w_rec[h * HH + k];
}

// ---------------- f32 GEMM: xw[n,h] = sum_k X[n,k] * w_inT[k,h] ----------------
#define BM 128
#define BN 128
#define BK 32
__global__ __launch_bounds__(256) void gemm_xw(const float* __restrict__ X,
                                               const float* __restrict__ WT,
                                               float* __restrict__ OutXW) {
    __shared__ __align__(16) float XsT[BK][BM + 4];   // transposed: [k][row]
    __shared__ __align__(16) float Ws[BK][BN + 4];    // [k][col]
    int tid = threadIdx.x;
    int n0 = blockIdx.x * BM;
    int h0 = blockIdx.y * BN;
    int ty = tid >> 4, tx = tid & 15;
    float acc[8][8] = {};

    for (int kc = 0; kc < HH; kc += BK) {
        {
            int r = tid & 127, kseg = (tid >> 7) * 16;
            const float* src = X + (size_t)(n0 + r) * HH + kc + kseg;
#pragma unroll
            for (int q = 0; q < 4; q++) {
                float4 xv = *(const float4*)(src + q * 4);
                XsT[kseg + q * 4 + 0][r] = xv.x;
                XsT[kseg + q * 4 + 1][r] = xv.y;
                XsT[kseg + q * 4 + 2][r] = xv.z;
                XsT[kseg + q * 4 + 3][r] = xv.w;
            }
        }
        {
            int krow = tid >> 3, cs = (tid & 7) * 16;
            const float* src = WT + (size_t)(kc + krow) * HH + h0 + cs;
#pragma unroll
            for (int q = 0; q < 4; q++) {
                float4 wv = *(const float4*)(src + q * 4);
                *(float4*)&Ws[krow][cs + q * 4] = wv;
            }
        }
        __syncthreads();
#pragma unroll 4
        for (int kk = 0; kk < BK; kk++) {
            float4 a0 = *(const float4*)&XsT[kk][ty * 8];
            float4 a1 = *(const float4*)&XsT[kk][ty * 8 + 4];
            float4 b0 = *(const float4*)&Ws[kk][tx * 8];
            float4 b1 = *(const float4*)&Ws[kk][tx * 8 + 4];
            float a[8] = {a0.x, a0.y, a0.z, a0.w, a1.x, a1.y, a1.z, a1.w};
            float bb[8] = {b0.x, b0.y, b0.z, b0.w, b1.x, b1.y, b1.z, b1.w};
#pragma unroll
            for (int r = 0; r < 8; r++)
#pragma unroll
                for (int c = 0; c < 8; c++)
                    acc[r][c] += a[r] * bb[c];
        }
        __syncthreads();
    }
#pragma unroll
    for (int r = 0; r < 8; r++) {
        int n = n0 + ty * 8 + r;
        int b = n / TT;
        int t = n - b * TT;
        float* dst = OutXW + ((size_t)t * BB + b) * HH + h0 + tx * 8;
        float4 s0 = {acc[r][0], acc[r][1], acc[r][2], acc[r][3]};
        float4 s1 = {acc[r][4], acc[r][5], acc[r][6], acc[r][7]};
        *(float4*)dst = s0;
        *(float4*)(dst + 4) = s1;
    }
}

// ---------------- sequential LIF scan: producer/consumer wave pair per batch ----------------
// R6-verbatim arithmetic (h = lane+64j ownership, immediate per-spike gather in
// ascending s order, scalar NT spike stores). Change vs R6: w_recT rows 0..127
// (= masks m0,m1) are served from a 128KB LDS cache (lgkmcnt ~25cy) instead of
// L2 (~220cy); rows 128..255 (m2,m3) unchanged from global. Same values, same
// summation order -> bitwise-identical results.

// One LIF step; cur[] holds this step's xw row (from LDS ring).
#define STEP()                                                                      \
    do {                                                                            \
        bool z[4];                                                                  \
        _Pragma("unroll")                                                           \
        for (int j = 0; j < 4; j++) {                                               \
            float vd = vv[j] + am[j] * (ii[j] - vv[j]);     /* v + DT*tmi*(-v+i) */ \
            float id = ii[j] - bs[j] * ii[j];               /* i - DT*tsi*i    */   \
            z[j] = (vd - 1.0f) > 0.0f;                                              \
            float zf = z[j] ? 1.0f : 0.0f;                                          \
            vv[j] = z[j] ? 0.0f : vd;                                               \
            ii[j] = (id + cur[j]) + racc[j];                /* (i_dec+xw)+rec */    \
            __builtin_nontemporal_store(zf, &outp[stoff + j * 64]);                 \
            zl[j] = zf;                                                             \
        }                                                                           \
        stoff += BH;                                                                \
        unsigned long long m0 = __ballot(z[0]);                                     \
        unsigned long long m1 = __ballot(z[1]);                                     \
        unsigned long long m2 = __ballot(z[2]);                                     \
        unsigned long long m3 = __ballot(z[3]);                                     \
        racc[0] = 0.0f; racc[1] = 0.0f; racc[2] = 0.0f; racc[3] = 0.0f;             \
        if ((m0 | m1 | m2 | m3) != 0ull) {                                          \
            unsigned long long m;                                                   \
            m = m0;                                                                 \
            while (m) { int bit = __builtin_ctzll(m); m &= m - 1;                   \
                const float* wr = wcache + (size_t)(bit) * HH + lane;               \
                racc[0] += wr[0]; racc[1] += wr[64];                                \
                racc[2] += wr[128]; racc[3] += wr[192]; }                           \
            m = m1;                                                                 \
            while (m) { int bit = __builtin_ctzll(m); m &= m - 1;                   \
                const float* wr = wcache + (size_t)(64 + bit) * HH + lane;          \
                racc[0] += wr[0]; racc[1] += wr[64];                                \
                racc[2] += wr[128]; racc[3] += wr[192]; }                           \
            m = m2;                                                                 \
            while (m) { int bit = __builtin_ctzll(m); m &= m - 1;                   \
                const float* wr = w_recT + (size_t)(128 + bit) * HH + lane;         \
                racc[0] += wr[0]; racc[1] += wr[64];                                \
                racc[2] += wr[128]; racc[3] += wr[192]; }                           \
            m = m3;                                                                 \
            while (m) { int bit = __builtin_ctzll(m); m &= m - 1;                   \
                const float* wr = w_recT + (size_t)(192 + bit) * HH + lane;         \
                racc[0] += wr[0]; racc[1] += wr[64];                                \
                racc[2] += wr[128]; racc[3] += wr[192]; }                           \
        }                                                                           \
    } while (0)

__global__ __launch_bounds__(128) void scan_lif(const float* __restrict__ tau_syn,
                                                const float* __restrict__ tau_mem,
                                                const float* __restrict__ w_recT,
                                                float* __restrict__ outp) {
    const float DT = 0.001f;
    __shared__ __align__(16) float ring[2 * CH * HH];     // 16 KB: 2 slots x 8 rows x 1KB
    __shared__ __align__(16) float wcache[CROWS * HH];    // 128 KB: w_recT rows 0..127
    int b = blockIdx.x;
    int lane = threadIdx.x & 63;
    int wid = threadIdx.x >> 6;

    // ---- cooperative LDS fill of w_recT rows 0..127 (both waves, 128 threads) ----
    {
        const float4* src = (const float4*)w_recT;
        float4* dst = (float4*)wcache;
#pragma unroll
        for (int q = 0; q < (CROWS * HH / 4) / 128; ++q)
            dst[q * 128 + threadIdx.x] = src[q * 128 + threadIdx.x];
    }
    // (visibility of wcache to the consumer is covered by the first __syncthreads below)

    if (wid == 1) {
        // ---- producer: pre-stage chunk 0 into slot 0 ----
        float4 rb[CH];
#pragma unroll
        for (int r = 0; r < CH; ++r)
            rb[r] = *(const float4*)(outp + ((size_t)r * BB + b) * HH + 4 * lane);
#pragma unroll
        for (int r = 0; r < CH; ++r)
            *(float4*)&ring[r * HH + 4 * lane] = rb[r];
        __syncthreads();
        for (int c = 0; c < NCH; ++c) {
            if (c + 1 < NCH) {
                int t0 = (c + 1) * CH;
                int lb = ((c + 1) & 1) * (CH * HH);
                float4 sb[CH];
#pragma unroll
                for (int r = 0; r < CH; ++r)
                    sb[r] = *(const float4*)(outp + ((size_t)(t0 + r) * BB + b) * HH + 4 * lane);
#pragma unroll
                for (int r = 0; r < CH; ++r)
                    *(float4*)&ring[lb + r * HH + 4 * lane] = sb[r];
            }
            __syncthreads();
        }
        return;
    }

    // ---- consumer wave (R6-verbatim arithmetic) ----
    int off = b * HH + lane;
    float am[4], bs[4];
#pragma unroll
    for (int j = 0; j < 4; j++) {
        am[j] = DT * clip01(tau_mem[lane + 64 * j]);
        bs[j] = DT * clip01(tau_syn[lane + 64 * j]);
    }

    float vv[4] = {0.f, 0.f, 0.f, 0.f};
    float ii[4] = {0.f, 0.f, 0.f, 0.f};
    float racc[4] = {0.f, 0.f, 0.f, 0.f};
    float zl[4] = {0.f, 0.f, 0.f, 0.f};
    float cur[4], nxt[4];
    unsigned stoff = (unsigned)off;

    __syncthreads();   // chunk 0 staged + wcache filled

    for (int c = 0; c < NCH; ++c) {
        int lb = (c & 1) * (CH * HH);
#pragma unroll
        for (int j = 0; j < 4; j++)
            cur[j] = ring[lb + lane + 64 * j];
        for (int u = 0; u < CH - 1; ++u) {
#pragma unroll
            for (int j = 0; j < 4; j++)
                nxt[j] = ring[lb + (u + 1) * HH + lane + 64 * j];
            STEP();
#pragma unroll
            for (int j = 0; j < 4; j++)
                cur[j] = nxt[j];
        }
        STEP();        // u = CH-1
        __syncthreads();
    }

    // final state: z_f, v_f, i_f (all from registers)
#pragma unroll
    for (int j = 0; j < 4; j++) {
        outp[(size_t)TT * BH + b * HH + lane + 64 * j] = zl[j];
        outp[(size_t)TT * BH + BH + b * HH + lane + 64 * j] = vv[j];
        outp[(size_t)TT * BH + 2 * BH + b * HH + lane + 64 * j] = ii[j];
    }
}

extern "C" void kernel_launch(void* const* d_in, const int* in_sizes, int n_in,
                              void* d_out, int out_size, void* d_ws, size_t ws_size,
                              hipStream_t stream) {
    const float* x       = (const float*)d_in[0];
    const float* w_in    = (const float*)d_in[1];
    const float* w_rec   = (const float*)d_in[2];
    const float* tau_syn = (const float*)d_in[3];
    const float* tau_mem = (const float*)d_in[4];
    float* out = (float*)d_out;

    float* w_inT  = (float*)d_ws;           // 65536 floats
    float* w_recT = w_inT + HH * HH;        // 65536 floats

    transpose2<<<256, 256, 0, stream>>>(w_in, w_rec, w_inT, w_recT);

    dim3 ggrid((BB * TT) / BM, HH / BN);    // (1000, 2)
    gemm_xw<<<ggrid, 256, 0, stream>>>(x, w_inT, out);

    scan_lif<<<BB, 128, 0, stream>>>(tau_syn, tau_mem, w_recT, out);
}